// Round 2
// 207.881 us; speedup vs baseline: 1.0483x; 1.0483x over previous
//
#include <hip/hip_runtime.h>

#define S_LEN  2048
#define DMODEL 1024
#define NHEAD  16
#define DKDIM  64
#define NBATCH 2

typedef short bf16x8 __attribute__((ext_vector_type(8)));
typedef float f32x4  __attribute__((ext_vector_type(4)));

__device__ __forceinline__ unsigned short f2b(float f){
  unsigned int x = __float_as_uint(f);
  return (unsigned short)((x + 0x7FFFu + ((x >> 16) & 1u)) >> 16);  // RNE
}
__device__ __forceinline__ bf16x8 ld8(const unsigned short* p){
  return *reinterpret_cast<const bf16x8*>(p);
}
// async global->LDS DMA, 16B per lane; lds base must be wave-uniform (HW adds lane*16)
__device__ __forceinline__ void gld16(const unsigned short* g, unsigned short* l){
  __builtin_amdgcn_global_load_lds(
      (const __attribute__((address_space(1))) unsigned int*)(uintptr_t)g,
      (__attribute__((address_space(3))) unsigned int*)(uintptr_t)l,
      16, 0, 0);
}

// ---------------- X f32 -> bf16 convert ----------------
__global__ __launch_bounds__(256) void convert_x(
    const float* __restrict__ X, unsigned short* __restrict__ Xc)
{
  const size_t i0 = ((size_t)blockIdx.x * 256 + threadIdx.x) * 8;
  const float4 a = *reinterpret_cast<const float4*>(X + i0);
  const float4 b = *reinterpret_cast<const float4*>(X + i0 + 4);
  bf16x8 o;
  o[0]=(short)f2b(a.x); o[1]=(short)f2b(a.y); o[2]=(short)f2b(a.z); o[3]=(short)f2b(a.w);
  o[4]=(short)f2b(b.x); o[5]=(short)f2b(b.y); o[6]=(short)f2b(b.z); o[7]=(short)f2b(b.w);
  *reinterpret_cast<bf16x8*>(Xc + i0) = o;
}

// ---------------- weight transpose+convert: Wt[n*1024+k] = bf16(W[k*1024+n]) ----------------
__global__ __launch_bounds__(256) void transpose_w(
    const float* __restrict__ W0, const float* __restrict__ W1,
    const float* __restrict__ W2, const float* __restrict__ W3,
    unsigned short* __restrict__ Wt)
{
  __shared__ unsigned short tile[64][65];
  const float* src = (blockIdx.z==0)?W0:(blockIdx.z==1)?W1:(blockIdx.z==2)?W2:W3;
  unsigned short* dst = Wt + (size_t)blockIdx.z * DMODEL * DMODEL;
  const int r0 = blockIdx.x * 64, c0 = blockIdx.y * 64;
  #pragma unroll
  for(int t=0;t<16;t++){
    int idx = threadIdx.x + t*256;
    int r = idx >> 6, c = idx & 63;
    tile[r][c] = f2b(src[(size_t)(r0+r)*DMODEL + (c0+c)]);
  }
  __syncthreads();
  #pragma unroll
  for(int t=0;t<16;t++){
    int idx = threadIdx.x + t*256;
    int r = idx >> 6, c = idx & 63;
    dst[(size_t)(c0+r)*DMODEL + (r0+c)] = tile[c][r];
  }
}

// ---------------- QKV projection GEMM, m97-style (128x128 tile, BK=32, DMA staging) ----
// z=0 -> q [B,H,S,DK] (PRE-SCALED by 1/sqrt(DK)=0.125); z=1 -> k; z=2 -> v transposed
__global__ __launch_bounds__(256) void gemm_qkv(
    const unsigned short* __restrict__ Xc,
    const unsigned short* __restrict__ WtBase,
    const float* __restrict__ bq,
    const float* __restrict__ bk,
    const float* __restrict__ bv,
    unsigned short* __restrict__ q_ws,
    unsigned short* __restrict__ k_ws,
    unsigned short* __restrict__ vT_ws)
{
  __shared__ __align__(16) unsigned short sA[128][32];
  __shared__ __align__(16) unsigned short sB[128][32];
  const int z = blockIdx.z;
  const unsigned short* Wt   = WtBase + (size_t)z * DMODEL * DMODEL;
  const float* bias = (z==0) ? bq : ((z==1) ? bk : bv);
  const float scl = (z==0) ? 0.125f : 1.0f;   // fold 1/sqrt(DK) into q (exact pow2)
  const int m0 = blockIdx.x * 128, n0 = blockIdx.y * 128;
  const int tid = threadIdx.x;
  const int w = tid >> 6, lane = tid & 63, quad = lane >> 4, lm = lane & 15;
  const int wm = (w & 1) * 64, wn = (w >> 1) * 64;
  const int srow = lane >> 2, scol = (lane & 3) * 8;   // staging lane coords

  f32x4 acc[4][4];
  #pragma unroll
  for(int i=0;i<4;i++)
    #pragma unroll
    for(int j=0;j<4;j++){ f32x4 z4 = {0.f,0.f,0.f,0.f}; acc[i][j] = z4; }

  for(int k0=0;k0<DMODEL;k0+=32){
    #pragma unroll
    for(int j=0;j<2;j++){
      gld16(Xc + (size_t)(m0 + w*32 + j*16 + srow)*DMODEL + k0 + scol, &sA[w*32 + j*16][0]);
      gld16(Wt + (size_t)(n0 + w*32 + j*16 + srow)*DMODEL + k0 + scol, &sB[w*32 + j*16][0]);
    }
    __syncthreads();
    bf16x8 a[4], b[4];
    #pragma unroll
    for(int i=0;i<4;i++) a[i] = ld8(&sA[wm + i*16 + lm][quad*8]);
    #pragma unroll
    for(int j=0;j<4;j++) b[j] = ld8(&sB[wn + j*16 + lm][quad*8]);
    #pragma unroll
    for(int i=0;i<4;i++)
      #pragma unroll
      for(int j=0;j<4;j++)
        acc[i][j] = __builtin_amdgcn_mfma_f32_16x16x32_bf16(a[i], b[j], acc[i][j], 0, 0, 0);
    __syncthreads();
  }

  #pragma unroll
  for(int j=0;j<4;j++){
    const int n  = n0 + wn + j*16 + lm;
    const float bb = bias[n] * scl;
    const int h_ = n >> 6, d_ = n & 63;
    #pragma unroll
    for(int i=0;i<4;i++){
      #pragma unroll
      for(int r=0;r<4;r++){
        const int m  = m0 + wm + i*16 + quad*4 + r;     // C/D: row = quad*4+reg
        const int b_ = m >> 11, s_ = m & 2047;
        const unsigned short o = f2b(fmaf(acc[i][j][r], scl, bb));
        if(z == 0)      q_ws [((size_t)(b_*NHEAD + h_)*S_LEN + s_)*DKDIM + d_] = o;
        else if(z == 1) k_ws [((size_t)(b_*NHEAD + h_)*S_LEN + s_)*DKDIM + d_] = o;
        else            vT_ws[((size_t)(b_*NHEAD + h_)*DKDIM + d_)*S_LEN + s_] = o;
      }
    }
  }
}

// ---------------- flash attention v5: swapped QK^T -> vectorized P path ----------------
// 4 waves/block, 128 q-rows/block, full K-range per wave. 64-col K/V tiles staged
// in padded LDS (shared by all waves; double-buffered; loads issued a tile ahead).
// QK^T computed TRANSPOSED (mfma(K,Q) -> D[j][qrow]) so each lane holds 4 consecutive
// j-values of one q-row: P packs via (bits+0x8000)>>16 round-half-up + v_perm_b32
// (NOT v_cvt_pk_bf16_f32 -- it truncates on gfx950; cost us absmax 1.8e-3 in v4),
// one ds_write_b64 into an XOR-swizzled unpadded P buffer (low-conflict writes,
// conflict-free b128 reads). No-max softmax; q pre-scaled by 0.125 in gemm_qkv.
__global__ __launch_bounds__(256) void flash_attn(
    const unsigned short* __restrict__ q_ws,
    const unsigned short* __restrict__ k_ws,
    const unsigned short* __restrict__ vT_ws,
    unsigned short* __restrict__ attn_c)
{
  __shared__ __align__(16) unsigned short kt[2][64][72];   // [j][d], padded rows
  __shared__ __align__(16) unsigned short vt[2][64][72];   // [d][j], padded rows
  __shared__ __align__(16) unsigned short p_lds[4*32*64];  // flat [wave][qrow32][j64], swizzled
  const int bh = blockIdx.y;
  const int b_ = bh >> 4, h_ = bh & 15;
  const int tid = threadIdx.x;
  const int w = tid >> 6, lane = tid & 63, quad = lane >> 4, lm = lane & 15;
  const int r0 = blockIdx.x * 128 + w * 32;
  const int swz = lm & 14;                                 // P-buffer XOR key (keeps b64 slots intact)

  const unsigned short* qp = q_ws  + ((size_t)bh * S_LEN + r0) * DKDIM;
  const unsigned short* kp = k_ws  + (size_t)bh * S_LEN * DKDIM;
  const unsigned short* vp = vT_ws + (size_t)bh * DKDIM * S_LEN;

  // Q B-frags for 2 row-groups x 2 k-chunks
  bf16x8 qf[2][2];
  #pragma unroll
  for(int g=0;g<2;g++)
    #pragma unroll
    for(int c=0;c<2;c++)
      qf[g][c] = ld8(qp + (size_t)(g*16 + lm)*DKDIM + c*32 + quad*8);

  f32x4 o_acc[2][4];
  #pragma unroll
  for(int g=0;g<2;g++)
    #pragma unroll
    for(int d=0;d<4;d++){ f32x4 z4 = {0.f,0.f,0.f,0.f}; o_acc[g][d] = z4; }
  float rsum[2] = {0.f, 0.f};                              // lane-local row partial sums

  // staging lane coords: wave w owns K j-rows / V d-rows [w*16, w*16+16)
  const int srow = lane >> 3;            // 0..7
  const int scol = (lane & 7) * 8;       // shorts within 128B row

  bf16x8 kreg[2], vreg[2];
  #pragma unroll
  for(int p=0;p<2;p++){
    kreg[p] = ld8(kp + (size_t)(w*16 + p*8 + srow)*DKDIM + scol);
    vreg[p] = ld8(vp + (size_t)(w*16 + p*8 + srow)*S_LEN + scol);
  }
  #pragma unroll
  for(int p=0;p<2;p++){
    *reinterpret_cast<bf16x8*>(&kt[0][w*16 + p*8 + srow][scol]) = kreg[p];
    *reinterpret_cast<bf16x8*>(&vt[0][w*16 + p*8 + srow][scol]) = vreg[p];
  }
  __syncthreads();

  for(int t=0;t<32;t++){
    const int buf = t & 1;
    if(t < 31){
      const int jn = (t+1)*64;
      #pragma unroll
      for(int p=0;p<2;p++){
        kreg[p] = ld8(kp + (size_t)(jn + w*16 + p*8 + srow)*DKDIM + scol);
        vreg[p] = ld8(vp + (size_t)(w*16 + p*8 + srow)*S_LEN + jn + scol);
      }
    }
    // QK^T transposed: D[j = s*16+quad*4+r][qrow = g*16+lm]; exp; packed P write
    #pragma unroll
    for(int s=0;s<4;s++){
      bf16x8 k0 = ld8(&kt[buf][s*16 + lm][quad*8]);
      bf16x8 k1 = ld8(&kt[buf][s*16 + lm][32 + quad*8]);
      #pragma unroll
      for(int g=0;g<2;g++){
        f32x4 z4 = {0.f,0.f,0.f,0.f};
        f32x4 sc = __builtin_amdgcn_mfma_f32_16x16x32_bf16(k0, qf[g][0], z4, 0,0,0);
        sc       = __builtin_amdgcn_mfma_f32_16x16x32_bf16(k1, qf[g][1], sc, 0,0,0);
        const float e0 = __expf(sc[0]);
        const float e1 = __expf(sc[1]);
        const float e2 = __expf(sc[2]);
        const float e3 = __expf(sc[3]);
        rsum[g] += (e0 + e1) + (e2 + e3);
        // round-half-up bf16 pack: u>>16 is rhu(e); v_perm_b32 packs {u0.hi16, u1.hi16}
        const unsigned int u0 = __float_as_uint(e0) + 0x8000u;
        const unsigned int u1 = __float_as_uint(e1) + 0x8000u;
        const unsigned int u2 = __float_as_uint(e2) + 0x8000u;
        const unsigned int u3 = __float_as_uint(e3) + 0x8000u;
        uint2 pk;
        pk.x = __builtin_amdgcn_perm(u1, u0, 0x07060302u);
        pk.y = __builtin_amdgcn_perm(u3, u2, 0x07060302u);
        *reinterpret_cast<uint2*>(
          &p_lds[((w*32 + g*16 + lm) << 6) + (((s*4 + quad) ^ swz) << 2)]) = pk;
      }
    }
    // P·V  (A-frag read: row = qrow, 8 consecutive j via two adjacent swizzled slots)
    #pragma unroll
    for(int ch=0;ch<2;ch++){
      const int sl = ((ch*8 + quad*2) ^ swz) << 2;
      bf16x8 pf0 = ld8(&p_lds[((w*32      + lm) << 6) + sl]);
      bf16x8 pf1 = ld8(&p_lds[((w*32 + 16 + lm) << 6) + sl]);
      #pragma unroll
      for(int d=0;d<4;d++){
        bf16x8 vf = ld8(&vt[buf][d*16 + lm][ch*32 + quad*8]);
        o_acc[0][d] = __builtin_amdgcn_mfma_f32_16x16x32_bf16(pf0, vf, o_acc[0][d], 0,0,0);
        o_acc[1][d] = __builtin_amdgcn_mfma_f32_16x16x32_bf16(pf1, vf, o_acc[1][d], 0,0,0);
      }
    }
    if(t < 31){
      const int nb = 1 - buf;
      #pragma unroll
      for(int p=0;p<2;p++){
        *reinterpret_cast<bf16x8*>(&kt[nb][w*16 + p*8 + srow][scol]) = kreg[p];
        *reinterpret_cast<bf16x8*>(&vt[nb][w*16 + p*8 + srow][scol]) = vreg[p];
      }
    }
    __syncthreads();
  }

  // row sums: reduce across the 4 quads (lanes lm hold row g*16+lm), then
  // redistribute to the o_acc layout (row = g*16+quad*4+r) via per-lane shfl
  float rinv[2][4];
  #pragma unroll
  for(int g=0;g<2;g++){
    float s2 = rsum[g];
    s2 += __shfl_xor(s2, 16);
    s2 += __shfl_xor(s2, 32);
    #pragma unroll
    for(int r=0;r<4;r++)
      rinv[g][r] = __frcp_rn(__shfl(s2, quad*4 + r));
  }

  #pragma unroll
  for(int g=0;g<2;g++)
    #pragma unroll
    for(int d=0;d<4;d++)
      #pragma unroll
      for(int r=0;r<4;r++){
        const int row = r0 + g*16 + quad*4 + r;
        const int col = h_*DKDIM + d*16 + lm;
        attn_c[((size_t)(b_*S_LEN + row))*DMODEL + col] = f2b(o_acc[g][d][r] * rinv[g][r]);
      }
}

// ---------------- output projection, m97-style: attn_c @ Wo + bo -> d_out (f32) ----------
__global__ __launch_bounds__(256) void gemm_out(
    const unsigned short* __restrict__ A,
    const unsigned short* __restrict__ Wt,
    const float* __restrict__ bias,
    float* __restrict__ out)
{
  __shared__ __align__(16) unsigned short sA[128][32];
  __shared__ __align__(16) unsigned short sB[128][32];
  const int m0 = blockIdx.x * 128, n0 = blockIdx.y * 128;
  const int tid = threadIdx.x;
  const int w = tid >> 6, lane = tid & 63, quad = lane >> 4, lm = lane & 15;
  const int wm = (w & 1) * 64, wn = (w >> 1) * 64;
  const int srow = lane >> 2, scol = (lane & 3) * 8;

  f32x4 acc[4][4];
  #pragma unroll
  for(int i=0;i<4;i++)
    #pragma unroll
    for(int j=0;j<4;j++){ f32x4 z4 = {0.f,0.f,0.f,0.f}; acc[i][j] = z4; }

  for(int k0=0;k0<DMODEL;k0+=32){
    #pragma unroll
    for(int j=0;j<2;j++){
      gld16(A  + (size_t)(m0 + w*32 + j*16 + srow)*DMODEL + k0 + scol, &sA[w*32 + j*16][0]);
      gld16(Wt + (size_t)(n0 + w*32 + j*16 + srow)*DMODEL + k0 + scol, &sB[w*32 + j*16][0]);
    }
    __syncthreads();
    bf16x8 a[4], b[4];
    #pragma unroll
    for(int i=0;i<4;i++) a[i] = ld8(&sA[wm + i*16 + lm][quad*8]);
    #pragma unroll
    for(int j=0;j<4;j++) b[j] = ld8(&sB[wn + j*16 + lm][quad*8]);
    #pragma unroll
    for(int i=0;i<4;i++)
      #pragma unroll
      for(int j=0;j<4;j++)
        acc[i][j] = __builtin_amdgcn_mfma_f32_16x16x32_bf16(a[i], b[j], acc[i][j], 0, 0, 0);
    __syncthreads();
  }

  #pragma unroll
  for(int j=0;j<4;j++){
    const int n = n0 + wn + j*16 + lm;
    const float bb = bias[n];
    #pragma unroll
    for(int i=0;i<4;i++){
      #pragma unroll
      for(int r=0;r<4;r++){
        const int m = m0 + wm + i*16 + quad*4 + r;
        out[(size_t)m*DMODEL + n] = acc[i][j][r] + bb;
      }
    }
  }
}

extern "C" void kernel_launch(void* const* d_in, const int* in_sizes, int n_in,
                              void* d_out, int out_size, void* d_ws, size_t ws_size,
                              hipStream_t stream)
{
  const float* X  = (const float*)d_in[0];
  const float* Wq = (const float*)d_in[1];
  const float* bq = (const float*)d_in[2];
  const float* Wk = (const float*)d_in[3];
  const float* bk = (const float*)d_in[4];
  const float* Wv = (const float*)d_in[5];
  const float* bv = (const float*)d_in[6];
  const float* Wo = (const float*)d_in[7];
  const float* bo = (const float*)d_in[8];

  unsigned short* ws = (unsigned short*)d_ws;
  const size_t WMAT = (size_t)DMODEL * DMODEL;                 // 1M elems
  const size_t QKV  = (size_t)NBATCH * NHEAD * S_LEN * DKDIM;  // 4M elems
  unsigned short* Wt     = ws;               // 4 transposed bf16 weights (4M elems)
  unsigned short* Xc     = ws + 4*WMAT;      // bf16 X (4M elems)
  unsigned short* q_ws   = Xc + QKV;
  unsigned short* k_ws   = q_ws + QKV;
  unsigned short* vT_ws  = k_ws + QKV;
  unsigned short* attn_c = Xc;               // alias: Xc dead after gemm_qkv
  float* out = (float*)d_out;

  convert_x  <<<dim3(2048),     256, 0, stream>>>(X, Xc);
  transpose_w<<<dim3(16,16,4),  256, 0, stream>>>(Wq, Wk, Wv, Wo, Wt);
  gemm_qkv   <<<dim3(32,8,3),   256, 0, stream>>>(Xc, Wt, bq, bk, bv, q_ws, k_ws, vT_ws);
  flash_attn <<<dim3(16,32),    256, 0, stream>>>(q_ws, k_ws, vT_ws, attn_c);
  gemm_out   <<<dim3(32,8),     256, 0, stream>>>(attn_c, Wt + 3*WMAT, bo, out);
}

// Round 3
// 202.328 us; speedup vs baseline: 1.0771x; 1.0274x over previous
//
#include <hip/hip_runtime.h>

#define S_LEN  2048
#define DMODEL 1024
#define NHEAD  16
#define DKDIM  64
#define NBATCH 2

typedef short bf16x8 __attribute__((ext_vector_type(8)));
typedef float f32x4  __attribute__((ext_vector_type(4)));
typedef float f32x16 __attribute__((ext_vector_type(16)));

__device__ __forceinline__ unsigned short f2b(float f){
  unsigned int x = __float_as_uint(f);
  return (unsigned short)((x + 0x7FFFu + ((x >> 16) & 1u)) >> 16);  // RNE
}
__device__ __forceinline__ bf16x8 ld8(const unsigned short* p){
  return *reinterpret_cast<const bf16x8*>(p);
}
// async global->LDS DMA, 16B per lane; lds base must be wave-uniform (HW adds lane*16)
__device__ __forceinline__ void gld16(const unsigned short* g, unsigned short* l){
  __builtin_amdgcn_global_load_lds(
      (const __attribute__((address_space(1))) unsigned int*)(uintptr_t)g,
      (__attribute__((address_space(3))) unsigned int*)(uintptr_t)l,
      16, 0, 0);
}
__device__ __forceinline__ float fexp2(float x){
#if __has_builtin(__builtin_amdgcn_exp2f)
  return __builtin_amdgcn_exp2f(x);
#else
  return exp2f(x);
#endif
}
// v_permlane32_swap_b32: new a[l<32]=old a[l<32], a[l>=32]=old b[l-32];
//                        new b[l<32]=old a[l+32], b[l>=32]=old b[l>=32]
__device__ __forceinline__ void pl32swap(unsigned int &a, unsigned int &b){
  asm("v_permlane32_swap_b32 %0, %1" : "+v"(a), "+v"(b));
}

// ---------------- X f32 -> bf16 convert ----------------
__global__ __launch_bounds__(256) void convert_x(
    const float* __restrict__ X, unsigned short* __restrict__ Xc)
{
  const size_t i0 = ((size_t)blockIdx.x * 256 + threadIdx.x) * 8;
  const float4 a = *reinterpret_cast<const float4*>(X + i0);
  const float4 b = *reinterpret_cast<const float4*>(X + i0 + 4);
  bf16x8 o;
  o[0]=(short)f2b(a.x); o[1]=(short)f2b(a.y); o[2]=(short)f2b(a.z); o[3]=(short)f2b(a.w);
  o[4]=(short)f2b(b.x); o[5]=(short)f2b(b.y); o[6]=(short)f2b(b.z); o[7]=(short)f2b(b.w);
  *reinterpret_cast<bf16x8*>(Xc + i0) = o;
}

// ---------------- weight transpose+convert: Wt[n*1024+k] = bf16(W[k*1024+n]) ----------------
__global__ __launch_bounds__(256) void transpose_w(
    const float* __restrict__ W0, const float* __restrict__ W1,
    const float* __restrict__ W2, const float* __restrict__ W3,
    unsigned short* __restrict__ Wt)
{
  __shared__ unsigned short tile[64][65];
  const float* src = (blockIdx.z==0)?W0:(blockIdx.z==1)?W1:(blockIdx.z==2)?W2:W3;
  unsigned short* dst = Wt + (size_t)blockIdx.z * DMODEL * DMODEL;
  const int r0 = blockIdx.x * 64, c0 = blockIdx.y * 64;
  #pragma unroll
  for(int t=0;t<16;t++){
    int idx = threadIdx.x + t*256;
    int r = idx >> 6, c = idx & 63;
    tile[r][c] = f2b(src[(size_t)(r0+r)*DMODEL + (c0+c)]);
  }
  __syncthreads();
  #pragma unroll
  for(int t=0;t<16;t++){
    int idx = threadIdx.x + t*256;
    int r = idx >> 6, c = idx & 63;
    dst[(size_t)(c0+r)*DMODEL + (r0+c)] = tile[c][r];
  }
}

// ---------------- QKV projection GEMM, m97-style (128x128 tile, BK=32, DMA staging) ----
// z=0 -> q [B,H,S,DK] (PRE-SCALED by 0.125*log2(e) so attn can use exp2); z=1 -> k;
// z=2 -> v transposed [B,H,DK,S]
__global__ __launch_bounds__(256) void gemm_qkv(
    const unsigned short* __restrict__ Xc,
    const unsigned short* __restrict__ WtBase,
    const float* __restrict__ bq,
    const float* __restrict__ bk,
    const float* __restrict__ bv,
    unsigned short* __restrict__ q_ws,
    unsigned short* __restrict__ k_ws,
    unsigned short* __restrict__ vT_ws)
{
  __shared__ __align__(16) unsigned short sA[128][32];
  __shared__ __align__(16) unsigned short sB[128][32];
  const int z = blockIdx.z;
  const unsigned short* Wt   = WtBase + (size_t)z * DMODEL * DMODEL;
  const float* bias = (z==0) ? bq : ((z==1) ? bk : bv);
  const float scl = (z==0) ? 0.18033688011f : 1.0f;   // 0.125 * log2(e)
  const int m0 = blockIdx.x * 128, n0 = blockIdx.y * 128;
  const int tid = threadIdx.x;
  const int w = tid >> 6, lane = tid & 63, quad = lane >> 4, lm = lane & 15;
  const int wm = (w & 1) * 64, wn = (w >> 1) * 64;
  const int srow = lane >> 2, scol = (lane & 3) * 8;   // staging lane coords

  f32x4 acc[4][4];
  #pragma unroll
  for(int i=0;i<4;i++)
    #pragma unroll
    for(int j=0;j<4;j++){ f32x4 z4 = {0.f,0.f,0.f,0.f}; acc[i][j] = z4; }

  for(int k0=0;k0<DMODEL;k0+=32){
    #pragma unroll
    for(int j=0;j<2;j++){
      gld16(Xc + (size_t)(m0 + w*32 + j*16 + srow)*DMODEL + k0 + scol, &sA[w*32 + j*16][0]);
      gld16(Wt + (size_t)(n0 + w*32 + j*16 + srow)*DMODEL + k0 + scol, &sB[w*32 + j*16][0]);
    }
    __syncthreads();
    bf16x8 a[4], b[4];
    #pragma unroll
    for(int i=0;i<4;i++) a[i] = ld8(&sA[wm + i*16 + lm][quad*8]);
    #pragma unroll
    for(int j=0;j<4;j++) b[j] = ld8(&sB[wn + j*16 + lm][quad*8]);
    #pragma unroll
    for(int i=0;i<4;i++)
      #pragma unroll
      for(int j=0;j<4;j++)
        acc[i][j] = __builtin_amdgcn_mfma_f32_16x16x32_bf16(a[i], b[j], acc[i][j], 0, 0, 0);
    __syncthreads();
  }

  #pragma unroll
  for(int j=0;j<4;j++){
    const int n  = n0 + wn + j*16 + lm;
    const float bb = bias[n] * scl;
    const int h_ = n >> 6, d_ = n & 63;
    #pragma unroll
    for(int i=0;i<4;i++){
      #pragma unroll
      for(int r=0;r<4;r++){
        const int m  = m0 + wm + i*16 + quad*4 + r;     // C/D: row = quad*4+reg
        const int b_ = m >> 11, s_ = m & 2047;
        const unsigned short o = f2b(fmaf(acc[i][j][r], scl, bb));
        if(z == 0)      q_ws [((size_t)(b_*NHEAD + h_)*S_LEN + s_)*DKDIM + d_] = o;
        else if(z == 1) k_ws [((size_t)(b_*NHEAD + h_)*S_LEN + s_)*DKDIM + d_] = o;
        else            vT_ws[((size_t)(b_*NHEAD + h_)*DKDIM + d_)*S_LEN + s_] = o;
      }
    }
  }
}

// ---------------- flash attention v6: 32x32 MFMA, in-register P via permlane32_swap ----
// 2 waves/block, 32 q-rows/wave (64/block), grid (32,32)=1024 blocks -> 4 blocks/CU.
// K/V tiles (64 rows x 128B) staged via global_load_lds with PRE-SWIZZLED source
// (chunk ^= row&7) into linear LDS; fragment reads apply the same XOR -> uniform banks.
// Swapped QK^T (mfma(K,Q), 32x32x16) puts a full q-row's 32 scores in one lane pair;
// P redistributes to the PV A-frag IN REGISTERS: 2x v_permlane32_swap_b32 per k-chunk.
// No P LDS buffer at all. exp2 path: q pre-scaled by 0.125*log2e in gemm_qkv.
__global__ __launch_bounds__(128) void flash_attn(
    const unsigned short* __restrict__ q_ws,
    const unsigned short* __restrict__ k_ws,
    const unsigned short* __restrict__ vT_ws,
    unsigned short* __restrict__ attn_c)
{
  __shared__ __align__(16) unsigned short kt[2][64][64];   // [j][k], row-linear, chunk-swizzled
  __shared__ __align__(16) unsigned short vt[2][64][64];   // [d][j], row-linear, chunk-swizzled
  const int bh = blockIdx.y;
  const int b_ = bh >> 4, h_ = bh & 15;
  const int tid = threadIdx.x;
  const int w = tid >> 6, lane = tid & 63;
  const int l = lane & 31, hi = lane >> 5;
  const int r0 = blockIdx.x * 64 + w * 32;

  const unsigned short* qp = q_ws  + ((size_t)bh * S_LEN + r0) * DKDIM;
  const unsigned short* kp = k_ws  + (size_t)bh * S_LEN * DKDIM;
  const unsigned short* vp = vT_ws + (size_t)bh * DKDIM * S_LEN;

  // Q B-frags: qf[m] = Q[qrow=l][m*16 + hi*8 .. +8]
  bf16x8 qf[4];
  #pragma unroll
  for(int m=0;m<4;m++)
    qf[m] = ld8(qp + (size_t)l*DKDIM + m*16 + hi*8);

  f32x16 o_acc[2];
  #pragma unroll
  for(int d=0;d<2;d++)
    #pragma unroll
    for(int i=0;i<16;i++) o_acc[d][i] = 0.f;
  float rsum = 0.f;

  // staging: wave w owns rows [w*32, w*32+32) of both kt (K j-rows) and vt (V d-rows).
  // gld16 writes LDS linearly (base + lane*16); source chunk pre-swizzled by row&7.
  const int srow = (lane >> 3) & 7;          // row within 8-row group
  const int schk = (lane & 7) ^ srow;        // pre-swizzled global 16B-chunk index
  int kofs[4], vofs[4];                      // per-lane global offsets (shorts)
  #pragma unroll
  for(int p=0;p<4;p++){
    const int row = w*32 + p*8 + srow;       // row&7 == srow
    kofs[p] = row*DKDIM + schk*8;            // + t*4096 per tile
    vofs[p] = row*S_LEN + schk*8;            // + t*64 per tile
  }

  #pragma unroll
  for(int p=0;p<4;p++){
    gld16(kp + kofs[p], &kt[0][w*32 + p*8][0]);
    gld16(vp + vofs[p], &vt[0][w*32 + p*8][0]);
  }
  __syncthreads();

  for(int t=0;t<32;t++){
    const int buf = t & 1, nb = buf ^ 1;
    if(t < 31){
      #pragma unroll
      for(int p=0;p<4;p++){
        gld16(kp + (t+1)*4096 + kofs[p], &kt[nb][w*32 + p*8][0]);
        gld16(vp + (t+1)*64   + vofs[p], &vt[nb][w*32 + p*8][0]);
      }
    }
    #pragma unroll
    for(int jb=0;jb<2;jb++){
      // QK^T swapped: D[j][qrow], j-block of 32, K=64 via 4 mfmas
      f32x16 sacc;
      #pragma unroll
      for(int i=0;i<16;i++) sacc[i] = 0.f;
      #pragma unroll
      for(int m=0;m<4;m++){
        bf16x8 kf = ld8(&kt[buf][jb*32 + l][((2*m + hi) ^ (l & 7)) * 8]);
        sacc = __builtin_amdgcn_mfma_f32_32x32x16_bf16(kf, qf[m], sacc, 0, 0, 0);
      }
      // reg r -> j = jb*32 + (r&3) + 8*(r>>2) + 4*hi ; col = qrow = l
      // exp2 + round-half-up bf16 pack: run r2 = regs 4r2..4r2+3 -> pk[2r2], pk[2r2+1]
      unsigned int pk[8];
      float ea = 0.f;
      #pragma unroll
      for(int r2=0;r2<4;r2++){
        const float e0 = fexp2(sacc[4*r2+0]);
        const float e1 = fexp2(sacc[4*r2+1]);
        const float e2 = fexp2(sacc[4*r2+2]);
        const float e3 = fexp2(sacc[4*r2+3]);
        ea += (e0+e1)+(e2+e3);
        const unsigned int u0 = __float_as_uint(e0) + 0x8000u;
        const unsigned int u1 = __float_as_uint(e1) + 0x8000u;
        const unsigned int u2 = __float_as_uint(e2) + 0x8000u;
        const unsigned int u3 = __float_as_uint(e3) + 0x8000u;
        pk[2*r2]   = __builtin_amdgcn_perm(u1, u0, 0x07060302u);
        pk[2*r2+1] = __builtin_amdgcn_perm(u3, u2, 0x07060302u);
      }
      rsum += ea;
      // PV: per k-chunk c (j = jb*32+16c..+16), A-frag assembled by 2 permlane swaps:
      //   hi=0 lane needs (self run 2c, partner run 2c); hi=1 needs (partner 2c+1, self 2c+1)
      #pragma unroll
      for(int c=0;c<2;c++){
        unsigned int a0 = pk[4*c],   b0 = pk[4*c+2];
        unsigned int a1 = pk[4*c+1], b1 = pk[4*c+3];
        pl32swap(a0, b0);
        pl32swap(a1, b1);
        union { unsigned int u[4]; bf16x8 v; } pa;
        pa.u[0] = a0; pa.u[1] = a1; pa.u[2] = b0; pa.u[3] = b1;
        #pragma unroll
        for(int dblk=0;dblk<2;dblk++){
          bf16x8 vf = ld8(&vt[buf][dblk*32 + l][((jb*4 + 2*c + hi) ^ (l & 7)) * 8]);
          o_acc[dblk] = __builtin_amdgcn_mfma_f32_32x32x16_bf16(pa.v, vf, o_acc[dblk], 0, 0, 0);
        }
      }
    }
    __syncthreads();
  }

  // row-sum: lane (l,hi) holds partial over its j-halves for qrow=l; combine across hi
  rsum += __shfl_xor(rsum, 32);
  const float rinv_l = __frcp_rn(rsum);

  // O layout: D[qrow][d]: col = d = dblk*32 + l, row = qrow = (r&3)+8*(r>>2)+4*hi
  #pragma unroll
  for(int r=0;r<16;r++){
    const int qr = (r&3) + 8*(r>>2) + 4*hi;
    const float ri = __shfl(rinv_l, qr);
    const size_t ob = ((size_t)(b_*S_LEN + r0 + qr))*DMODEL + h_*DKDIM + l;
    attn_c[ob]      = f2b(o_acc[0][r] * ri);
    attn_c[ob + 32] = f2b(o_acc[1][r] * ri);
  }
}

// ---------------- output projection, m97-style: attn_c @ Wo + bo -> d_out (f32) ----------
__global__ __launch_bounds__(256) void gemm_out(
    const unsigned short* __restrict__ A,
    const unsigned short* __restrict__ Wt,
    const float* __restrict__ bias,
    float* __restrict__ out)
{
  __shared__ __align__(16) unsigned short sA[128][32];
  __shared__ __align__(16) unsigned short sB[128][32];
  const int m0 = blockIdx.x * 128, n0 = blockIdx.y * 128;
  const int tid = threadIdx.x;
  const int w = tid >> 6, lane = tid & 63, quad = lane >> 4, lm = lane & 15;
  const int wm = (w & 1) * 64, wn = (w >> 1) * 64;
  const int srow = lane >> 2, scol = (lane & 3) * 8;

  f32x4 acc[4][4];
  #pragma unroll
  for(int i=0;i<4;i++)
    #pragma unroll
    for(int j=0;j<4;j++){ f32x4 z4 = {0.f,0.f,0.f,0.f}; acc[i][j] = z4; }

  for(int k0=0;k0<DMODEL;k0+=32){
    #pragma unroll
    for(int j=0;j<2;j++){
      gld16(A  + (size_t)(m0 + w*32 + j*16 + srow)*DMODEL + k0 + scol, &sA[w*32 + j*16][0]);
      gld16(Wt + (size_t)(n0 + w*32 + j*16 + srow)*DMODEL + k0 + scol, &sB[w*32 + j*16][0]);
    }
    __syncthreads();
    bf16x8 a[4], b[4];
    #pragma unroll
    for(int i=0;i<4;i++) a[i] = ld8(&sA[wm + i*16 + lm][quad*8]);
    #pragma unroll
    for(int j=0;j<4;j++) b[j] = ld8(&sB[wn + j*16 + lm][quad*8]);
    #pragma unroll
    for(int i=0;i<4;i++)
      #pragma unroll
      for(int j=0;j<4;j++)
        acc[i][j] = __builtin_amdgcn_mfma_f32_16x16x32_bf16(a[i], b[j], acc[i][j], 0, 0, 0);
    __syncthreads();
  }

  #pragma unroll
  for(int j=0;j<4;j++){
    const int n = n0 + wn + j*16 + lm;
    const float bb = bias[n];
    #pragma unroll
    for(int i=0;i<4;i++){
      #pragma unroll
      for(int r=0;r<4;r++){
        const int m = m0 + wm + i*16 + quad*4 + r;
        out[(size_t)m*DMODEL + n] = acc[i][j][r] + bb;
      }
    }
  }
}

extern "C" void kernel_launch(void* const* d_in, const int* in_sizes, int n_in,
                              void* d_out, int out_size, void* d_ws, size_t ws_size,
                              hipStream_t stream)
{
  const float* X  = (const float*)d_in[0];
  const float* Wq = (const float*)d_in[1];
  const float* bq = (const float*)d_in[2];
  const float* Wk = (const float*)d_in[3];
  const float* bk = (const float*)d_in[4];
  const float* Wv = (const float*)d_in[5];
  const float* bv = (const float*)d_in[6];
  const float* Wo = (const float*)d_in[7];
  const float* bo = (const float*)d_in[8];

  unsigned short* ws = (unsigned short*)d_ws;
  const size_t WMAT = (size_t)DMODEL * DMODEL;                 // 1M elems
  const size_t QKV  = (size_t)NBATCH * NHEAD * S_LEN * DKDIM;  // 4M elems
  unsigned short* Wt     = ws;               // 4 transposed bf16 weights (4M elems)
  unsigned short* Xc     = ws + 4*WMAT;      // bf16 X (4M elems)
  unsigned short* q_ws   = Xc + QKV;
  unsigned short* k_ws   = q_ws + QKV;
  unsigned short* vT_ws  = k_ws + QKV;
  unsigned short* attn_c = Xc;               // alias: Xc dead after gemm_qkv
  float* out = (float*)d_out;

  convert_x  <<<dim3(2048),     256, 0, stream>>>(X, Xc);
  transpose_w<<<dim3(16,16,4),  256, 0, stream>>>(Wq, Wk, Wv, Wo, Wt);
  gemm_qkv   <<<dim3(32,8,3),   256, 0, stream>>>(Xc, Wt, bq, bk, bv, q_ws, k_ws, vT_ws);
  flash_attn <<<dim3(32,32),    128, 0, stream>>>(q_ws, k_ws, vT_ws, attn_c);
  gemm_out   <<<dim3(32,8),     256, 0, stream>>>(attn_c, Wt + 3*WMAT, bo, out);
}